// Round 2
// baseline (11182.331 us; speedup 1.0000x reference)
//
#include <hip/hip_runtime.h>

#define H_ 256
#define W_ 1216
#define HW_ (H_*W_)
#define B_ 2
#define C_ 64
#define Ns_ 20000
#define K_ 9
#define D_ 131
#define Dh_ 65

__device__ __forceinline__ float b2f(unsigned short u){
  union { unsigned int i; float f; } v; v.i = ((unsigned int)u) << 16; return v.f;
}
__device__ __forceinline__ unsigned short f2b(float f){
  union { float f; unsigned int i; } v; v.f = f;
  unsigned int r = (v.i + 0x7FFFu + ((v.i >> 16) & 1u)) >> 16;
  return (unsigned short)r;
}

// ---------------- fused conv0(relu)+conv1 ----------------
// x: (B,64,H,W) fp32. Outputs (bf16): y0 NCHW (update buffer u),
// y0t transposed (B,HW,64) for coalesced gathers, y1 NCHW.
#define TW 32
#define TH 8

__global__ __launch_bounds__(256) void conv01_kernel(
    const float* __restrict__ x,
    const float* __restrict__ w0, const float* __restrict__ b0,
    const float* __restrict__ w1, const float* __restrict__ b1,
    unsigned short* __restrict__ y0,
    unsigned short* __restrict__ y0t,
    unsigned short* __restrict__ y1)
{
  __shared__ unsigned short tile[64 * 10 * 34];   // [cin][10 rows][34 cols], halo 1
  int tid = threadIdx.x;
  int x0 = blockIdx.x * TW;
  int y0r = blockIdx.y * TH;
  int b = blockIdx.z;

  const float* xb = x + (size_t)b * 64 * HW_;
  for (int e = tid; e < 64 * 340; e += 256){
    int cin = e / 340; int r = e % 340; int ys = r / 34; int xs = r % 34;
    int gy = y0r + ys - 1, gx = x0 + xs - 1;
    unsigned short v = 0;
    if (gy >= 0 && gy < H_ && gx >= 0 && gx < W_)
      v = f2b(xb[(size_t)cin * HW_ + (size_t)gy * W_ + gx]);
    tile[e] = v;
  }
  __syncthreads();

  int px = tid & 31, py = tid >> 5;
  size_t pix = (size_t)(y0r + py) * W_ + (x0 + px);

  #pragma unroll 1
  for (int chunk = 0; chunk < 8; ++chunk){
    float acc0[8], acc1[8];
    #pragma unroll
    for (int i = 0; i < 8; ++i){ acc0[i] = b0[chunk*8+i]; acc1[i] = b1[chunk*8+i]; }

    #pragma unroll 1
    for (int cin = 0; cin < 64; ++cin){
      const unsigned short* tp = &tile[cin*340 + py*34 + px];
      float xv[9];
      #pragma unroll
      for (int dy = 0; dy < 3; ++dy)
        #pragma unroll
        for (int dx = 0; dx < 3; ++dx)
          xv[dy*3+dx] = b2f(tp[dy*34+dx]);
      const float* wp0 = w0 + ((size_t)(chunk*8)*64 + cin) * 9;
      const float* wp1 = w1 + ((size_t)(chunk*8)*64 + cin) * 9;
      #pragma unroll
      for (int i = 0; i < 8; ++i){
        #pragma unroll
        for (int t = 0; t < 9; ++t){
          acc0[i] += xv[t] * wp0[(size_t)i*576 + t];
          acc1[i] += xv[t] * wp1[(size_t)i*576 + t];
        }
      }
    }

    union { unsigned short s[8]; uint4 v; } q0u;
    #pragma unroll
    for (int i = 0; i < 8; ++i){
      int co = chunk*8 + i;
      float v0 = acc0[i]; v0 = v0 > 0.f ? v0 : 0.f;
      unsigned short q0 = f2b(v0);
      q0u.s[i] = q0;
      y0[((size_t)b*64 + co) * HW_ + pix] = q0;
      y1[((size_t)b*64 + co) * HW_ + pix] = f2b(acc1[i]);
    }
    *reinterpret_cast<uint4*>(&y0t[((size_t)b*HW_ + pix)*64 + chunk*8]) = q0u.v;
  }
}

// ---------------- conv2 + add y1 + relu -> out (fp32) ----------------
__global__ __launch_bounds__(256) void conv2_kernel(
    const unsigned short* __restrict__ u,
    const float* __restrict__ w, const float* __restrict__ bias,
    const unsigned short* __restrict__ yprev,
    float* __restrict__ out)
{
  __shared__ unsigned short tile[64 * 10 * 34];
  int tid = threadIdx.x;
  int x0 = blockIdx.x * TW;
  int y0r = blockIdx.y * TH;
  int b = blockIdx.z;

  const unsigned short* xb = u + (size_t)b * 64 * HW_;
  for (int e = tid; e < 64 * 340; e += 256){
    int cin = e / 340; int r = e % 340; int ys = r / 34; int xs = r % 34;
    int gy = y0r + ys - 1, gx = x0 + xs - 1;
    unsigned short v = 0;
    if (gy >= 0 && gy < H_ && gx >= 0 && gx < W_)
      v = xb[(size_t)cin * HW_ + (size_t)gy * W_ + gx];
    tile[e] = v;
  }
  __syncthreads();

  int px = tid & 31, py = tid >> 5;
  size_t pix = (size_t)(y0r + py) * W_ + (x0 + px);

  #pragma unroll 1
  for (int chunk = 0; chunk < 8; ++chunk){
    float acc[8];
    #pragma unroll
    for (int i = 0; i < 8; ++i) acc[i] = bias[chunk*8+i];

    #pragma unroll 1
    for (int cin = 0; cin < 64; ++cin){
      const unsigned short* tp = &tile[cin*340 + py*34 + px];
      float xv[9];
      #pragma unroll
      for (int dy = 0; dy < 3; ++dy)
        #pragma unroll
        for (int dx = 0; dx < 3; ++dx)
          xv[dy*3+dx] = b2f(tp[dy*34+dx]);
      const float* wp = w + ((size_t)(chunk*8)*64 + cin) * 9;
      #pragma unroll
      for (int i = 0; i < 8; ++i){
        #pragma unroll
        for (int t = 0; t < 9; ++t)
          acc[i] += xv[t] * wp[(size_t)i*576 + t];
      }
    }

    #pragma unroll
    for (int i = 0; i < 8; ++i){
      int co = chunk*8 + i;
      size_t idx = ((size_t)b*64 + co) * HW_ + pix;
      float v = acc[i] + b2f(yprev[idx]);
      v = v > 0.f ? v : 0.f;
      out[idx] = v;
    }
  }
}

// ---------------- gather + 2 MLPs + softmax + weighted sum + scatter ----------------
// one block per (n, b); 256 threads
__global__ __launch_bounds__(256) void attn_kernel(
    const unsigned short* __restrict__ d0t, const unsigned short* __restrict__ r0t,
    const int* __restrict__ pc_idx, const int* __restrict__ nbrs_idx,
    const float* __restrict__ disp,
    const float* __restrict__ dw1, const float* __restrict__ db1,
    const float* __restrict__ dw2, const float* __restrict__ db2,
    const float* __restrict__ rw1, const float* __restrict__ rb1,
    const float* __restrict__ rw2, const float* __restrict__ rb2,
    const float* __restrict__ dbias, const float* __restrict__ rbias,
    unsigned short* __restrict__ u_d, unsigned short* __restrict__ u_r)
{
  __shared__ float feats[9][132];   // [k][d]: d<64 fd, 64..127 fr, 128..130 disp
  __shared__ float ds_s[64], rs_s[64];
  __shared__ float hbuf[2][9][66];
  __shared__ float logitS[2][9];
  __shared__ float attnS[2][9];
  __shared__ int nbrS[9];

  int n = blockIdx.x, b = blockIdx.y;
  int tid = threadIdx.x;
  int s = pc_idx[(size_t)b * Ns_ + n];

  if (tid < 9) nbrS[tid] = nbrs_idx[((size_t)b * Ns_ + n) * K_ + tid];
  __syncthreads();

  // gather neighbor features (dnn) and center features (ds, rs)
  for (int e = tid; e < 64 * 10; e += 256){
    int k = e >> 6, c = e & 63;
    if (k < 9){
      int idx = nbrS[k];
      feats[k][c] = b2f(d0t[((size_t)b * HW_ + idx) * 64 + c]);  // dnn (temp)
    } else {
      ds_s[c] = b2f(d0t[((size_t)b * HW_ + s) * 64 + c]);
      rs_s[c] = b2f(r0t[((size_t)b * HW_ + s) * 64 + c]);
    }
  }
  if (tid < 27){
    int m = tid / 9, k = tid % 9;
    feats[k][128 + m] = disp[(((size_t)b * 3 + m) * Ns_ + n) * K_ + k];
  }
  __syncthreads();

  // fd = dnn - ds ; fr = dnn - rs   (r-path neighbors come from d0f: source quirk)
  for (int e = tid; e < 64 * 9; e += 256){
    int k = e / 64, c = e % 64;
    float dnn = feats[k][c];
    feats[k][64 + c] = dnn - rs_s[c];
    feats[k][c]      = dnn - ds_s[c];
  }
  __syncthreads();

  // hidden layer: 2 mlps x 9 k x 65 j
  for (int job = tid; job < 2 * 9 * 65; job += 256){
    int mlp = job / (9 * 65);
    int r = job % (9 * 65);
    int k = r / 65, j = r % 65;
    const float* w1 = mlp ? rw1 : dw1;
    float h = (mlp ? rb1 : db1)[j];
    for (int d = 0; d < D_; ++d) h += feats[k][d] * w1[(size_t)d * Dh_ + j];
    h = h > 0.f ? h : 0.2f * h;   // leaky relu 0.2
    hbuf[mlp][k][j] = h;
  }
  __syncthreads();

  // output layer -> logits
  for (int job = tid; job < 18; job += 256){
    int mlp = job / 9, k = job % 9;
    const float* w2 = mlp ? rw2 : dw2;
    float l = (mlp ? rb2 : db2)[0];
    for (int j = 0; j < Dh_; ++j) l += hbuf[mlp][k][j] * w2[j];
    logitS[mlp][k] = l;
  }
  __syncthreads();

  // softmax over K per mlp
  if (tid < 2){
    float m = logitS[tid][0];
    for (int k = 1; k < 9; ++k) m = fmaxf(m, logitS[tid][k]);
    float e[9], sum = 0.f;
    for (int k = 0; k < 9; ++k){ e[k] = __expf(logitS[tid][k] - m); sum += e[k]; }
    float inv = 1.f / sum;
    for (int k = 0; k < 9; ++k) attnS[tid][k] = e[k] * inv;
  }
  __syncthreads();

  // weighted sum + scatter. mask quirk: only channel 0 is replaced; c>=1 adds.
  if (tid < 128){
    int mlp = tid >> 6, c = tid & 63;
    float f = (mlp ? rbias : dbias)[c];
    #pragma unroll
    for (int k = 0; k < 9; ++k){
      float dnn = feats[k][c] + ds_s[c];   // both mlps use d-neighbors
      f += attnS[mlp][k] * dnn;
    }
    float base = (c == 0) ? 0.f : (mlp ? rs_s[c] : ds_s[c]);
    unsigned short* u = mlp ? u_r : u_d;
    u[((size_t)b * 64 + c) * HW_ + s] = f2b(base + f);
  }
}

// ---------------- launch ----------------
extern "C" void kernel_launch(void* const* d_in, const int* in_sizes, int n_in,
                              void* d_out, int out_size, void* d_ws, size_t ws_size,
                              hipStream_t stream)
{
  (void)in_sizes; (void)n_in; (void)out_size; (void)ws_size;

  const float* rgb       = (const float*)d_in[0];
  const float* sdepth    = (const float*)d_in[1];
  const int*   pc_idx    = (const int*)d_in[2];
  const int*   nbrs_idx  = (const int*)d_in[3];
  const float* nbrs_disp = (const float*)d_in[4];

  const float* d_conv0_w = (const float*)d_in[5];
  const float* d_conv0_b = (const float*)d_in[6];
  const float* d_conv1_w = (const float*)d_in[7];
  const float* d_conv1_b = (const float*)d_in[8];
  const float* d_conv2_w = (const float*)d_in[9];
  const float* d_conv2_b = (const float*)d_in[10];
  const float* r_conv0_w = (const float*)d_in[11];
  const float* r_conv0_b = (const float*)d_in[12];
  const float* r_conv1_w = (const float*)d_in[13];
  const float* r_conv1_b = (const float*)d_in[14];
  const float* r_conv2_w = (const float*)d_in[15];
  const float* r_conv2_b = (const float*)d_in[16];
  const float* d_w1 = (const float*)d_in[17];
  const float* d_b1 = (const float*)d_in[18];
  const float* d_w2 = (const float*)d_in[19];
  const float* d_b2 = (const float*)d_in[20];
  const float* r_w1 = (const float*)d_in[21];
  const float* r_b1 = (const float*)d_in[22];
  const float* r_w2 = (const float*)d_in[23];
  const float* r_b2 = (const float*)d_in[24];
  const float* d_bias = (const float*)d_in[25];
  const float* r_bias = (const float*)d_in[26];

  char* ws = (char*)d_ws;
  const size_t SZ = (size_t)B_ * C_ * HW_ * 2;   // bytes of one (B,C,H,W) bf16 tensor
  unsigned short* u_d = (unsigned short*)(ws + 0*SZ);
  unsigned short* u_r = (unsigned short*)(ws + 1*SZ);
  unsigned short* d1  = (unsigned short*)(ws + 2*SZ);
  unsigned short* r1  = (unsigned short*)(ws + 3*SZ);
  unsigned short* d0t = (unsigned short*)(ws + 4*SZ);
  unsigned short* r0t = (unsigned short*)(ws + 5*SZ);

  dim3 cgrid(W_/TW, H_/TH, B_);
  // depth branch: conv0(relu)+conv1
  conv01_kernel<<<cgrid, 256, 0, stream>>>(sdepth, d_conv0_w, d_conv0_b, d_conv1_w, d_conv1_b, u_d, d0t, d1);
  // rgb branch
  conv01_kernel<<<cgrid, 256, 0, stream>>>(rgb,    r_conv0_w, r_conv0_b, r_conv1_w, r_conv1_b, u_r, r0t, r1);

  // attention/scatter
  attn_kernel<<<dim3(Ns_, B_), 256, 0, stream>>>(
      d0t, r0t, pc_idx, nbrs_idx, nbrs_disp,
      d_w1, d_b1, d_w2, d_b2,
      r_w1, r_b1, r_w2, r_b2,
      d_bias, r_bias,
      u_d, u_r);

  float* out = (float*)d_out;
  const size_t OUTSZ = (size_t)B_ * C_ * HW_;
  conv2_kernel<<<cgrid, 256, 0, stream>>>(u_d, d_conv2_w, d_conv2_b, d1, out);
  conv2_kernel<<<cgrid, 256, 0, stream>>>(u_r, r_conv2_w, r_conv2_b, r1, out + OUTSZ);
}

// Round 3
// 2817.447 us; speedup vs baseline: 3.9690x; 3.9690x over previous
//
#include <hip/hip_runtime.h>

#define H_ 256
#define W_ 1216
#define HW_ (H_*W_)
#define B_ 2
#define Ns_ 20000
#define K_ 9
#define D_ 131
#define Dh_ 65

#define LSTR 72      // LDS shorts per position (64 cin + 8 pad; 16B-aligned, even bank spread)
#define TPOS 66      // positions per tile row (64 + 2 halo)

typedef __attribute__((ext_vector_type(8))) short bf16x8;
typedef __attribute__((ext_vector_type(4))) float f32x4;

__device__ __forceinline__ float b2f(unsigned short u){
  union { unsigned int i; float f; } v; v.i = ((unsigned int)u) << 16; return v.f;
}
__device__ __forceinline__ unsigned short f2b(float f){
  union { float f; unsigned int i; } v; v.f = f;
  unsigned int r = (v.i + 0x7FFFu + ((v.i >> 16) & 1u)) >> 16;
  return (unsigned short)r;
}

// ---------------- weight swizzle: fp32 (C,Cin,3,3) -> bf16 MFMA A-frag order ----------------
// Layout: [conv(6)][mtile(4)][kc(18)][lane(64)][j(8)]; k = kc*32 + quad*8 + j; tap=k>>6, cin=k&63
struct WPtrs { const float* w[6]; };

__global__ void prep_w(WPtrs wp, unsigned short* __restrict__ Asw){
  int blk = blockIdx.x;                 // 6*4*18 = 432
  int c = blk / 72, rem = blk % 72, mt = rem / 18, kc = rem % 18;
  int lane = threadIdx.x;               // 64
  const float* w = wp.w[c];
  int co = mt*16 + (lane & 15);
  int kb = kc*32 + (lane >> 4)*8;
  unsigned short* dst = Asw + ((size_t)blk*64 + lane)*8;
  #pragma unroll
  for (int j = 0; j < 8; ++j){
    int k = kb + j, tap = k >> 6, cin = k & 63;
    dst[j] = f2b(w[((size_t)co*64 + cin)*9 + tap]);
  }
}

// ---------------- fused conv0(relu)+conv1, implicit-GEMM MFMA ----------------
// x fp32 NCHW. y0t,u: bf16 (B,HW,64). y1out: fp32 NCHW (= d_out region).
__global__ __launch_bounds__(256,3) void conv01_mfma(
    const float* __restrict__ x,
    const unsigned short* __restrict__ Asw,   // conv0 at +0, conv1 at +36864
    const float* __restrict__ b0, const float* __restrict__ b1,
    unsigned short* __restrict__ y0t, unsigned short* __restrict__ u,
    float* __restrict__ y1out)
{
  __shared__ unsigned short tile[4*TPOS*LSTR];
  int tid = threadIdx.x;
  int c0 = blockIdx.x*64, r0 = blockIdx.y*2, b = blockIdx.z;

  // stage 4 rows x 66 cols x 64 cin, fp32 NCHW -> bf16 [pos][cin]
  {
    int cin = tid >> 2, row = tid & 3;
    int gy = r0 - 1 + row;
    bool rowok = (gy >= 0) && (gy < H_);
    const float* src = x + ((size_t)b*64 + cin)*HW_ + (size_t)gy*W_ + c0 - 1;
    unsigned short* dst = &tile[(size_t)row*TPOS*LSTR + cin];
    #pragma unroll 1
    for (int col = 0; col < TPOS; ++col){
      int gx = c0 - 1 + col;
      float v = (rowok && gx >= 0 && gx < W_) ? src[col] : 0.f;
      dst[col*LSTR] = f2b(v);
    }
  }
  __syncthreads();

  int wave = tid >> 6, lane = tid & 63;
  int quad = lane >> 4, l15 = lane & 15;
  int cobase = (wave & 1)*32;    // wave covers co [cobase, cobase+32)
  int prow = wave >> 1;          // wave covers row r0+prow, cols 0..63

  f32x4 acc[2][2][4];
  #pragma unroll
  for (int cv = 0; cv < 2; ++cv)
    #pragma unroll
    for (int mt = 0; mt < 2; ++mt)
      #pragma unroll
      for (int nt = 0; nt < 4; ++nt)
        acc[cv][mt][nt] = (f32x4){0.f,0.f,0.f,0.f};

  const unsigned short* Ap[2][2];
  #pragma unroll
  for (int cv = 0; cv < 2; ++cv)
    #pragma unroll
    for (int mt = 0; mt < 2; ++mt)
      Ap[cv][mt] = Asw + ((size_t)((cv*4 + (wave&1)*2 + mt)*18)*64 + lane)*8;

  int bbase = (prow*TPOS + l15)*LSTR + quad*8;

  #pragma unroll
  for (int tap = 0; tap < 9; ++tap){
    const int sh = (tap/3)*TPOS + (tap%3);
    #pragma unroll
    for (int cc = 0; cc < 2; ++cc){
      int kc = tap*2 + cc;
      bf16x8 a[2][2], bb[4];
      #pragma unroll
      for (int cv = 0; cv < 2; ++cv)
        #pragma unroll
        for (int mt = 0; mt < 2; ++mt)
          a[cv][mt] = *(const bf16x8*)(Ap[cv][mt] + (size_t)kc*512);
      int boff = bbase + sh*LSTR + cc*32;
      #pragma unroll
      for (int nt = 0; nt < 4; ++nt)
        bb[nt] = *(const bf16x8*)&tile[boff + nt*16*LSTR];
      #pragma unroll
      for (int cv = 0; cv < 2; ++cv)
        #pragma unroll
        for (int mt = 0; mt < 2; ++mt)
          #pragma unroll
          for (int nt = 0; nt < 4; ++nt)
            acc[cv][mt][nt] = __builtin_amdgcn_mfma_f32_16x16x32_bf16(
                a[cv][mt], bb[nt], acc[cv][mt][nt], 0, 0, 0);
    }
  }

  int gy = r0 + prow;
  #pragma unroll
  for (int mt = 0; mt < 2; ++mt){
    int co4 = cobase + mt*16 + quad*4;
    f32x4 bias0 = *(const f32x4*)&b0[co4];
    f32x4 bias1 = *(const f32x4*)&b1[co4];
    #pragma unroll
    for (int nt = 0; nt < 4; ++nt){
      int gx = c0 + nt*16 + l15;
      size_t gpix = (size_t)gy*W_ + gx;
      f32x4 v0 = acc[0][mt][nt] + bias0;
      ushort4 q;
      q.x = f2b(fmaxf(v0.x,0.f)); q.y = f2b(fmaxf(v0.y,0.f));
      q.z = f2b(fmaxf(v0.z,0.f)); q.w = f2b(fmaxf(v0.w,0.f));
      size_t toff = ((size_t)b*HW_ + gpix)*64 + co4;
      *(ushort4*)&y0t[toff] = q;
      *(ushort4*)&u[toff]   = q;
      f32x4 v1 = acc[1][mt][nt] + bias1;
      float* yo = y1out + ((size_t)b*64 + co4)*HW_ + gpix;
      yo[(size_t)0*HW_] = v1.x; yo[(size_t)1*HW_] = v1.y;
      yo[(size_t)2*HW_] = v1.z; yo[(size_t)3*HW_] = v1.w;
    }
  }
}

// ---------------- conv2 + add(out-resident y1) + relu, implicit-GEMM MFMA ----------------
__global__ __launch_bounds__(256,3) void conv2_mfma(
    const unsigned short* __restrict__ ut,    // (B,HW,64) bf16
    const unsigned short* __restrict__ Asw,   // this conv's swizzled base
    const float* __restrict__ bias,
    float* __restrict__ out)                  // fp32 NCHW; holds y1; read-add-write
{
  __shared__ unsigned short tile[4*TPOS*LSTR];
  int tid = threadIdx.x;
  int c0 = blockIdx.x*64, r0 = blockIdx.y*2, b = blockIdx.z;

  #pragma unroll 1
  for (int e = tid; e < 4*TPOS*8; e += 256){
    int pos = e >> 3, ch = e & 7;
    int row = pos / TPOS, col = pos % TPOS;
    int gy = r0 - 1 + row, gx = c0 - 1 + col;
    uint4 v = {0u,0u,0u,0u};
    if (gy >= 0 && gy < H_ && gx >= 0 && gx < W_)
      v = *(const uint4*)&ut[((size_t)b*HW_ + (size_t)gy*W_ + gx)*64 + ch*8];
    *(uint4*)&tile[pos*LSTR + ch*8] = v;
  }
  __syncthreads();

  int wave = tid >> 6, lane = tid & 63;
  int quad = lane >> 4, l15 = lane & 15;
  int cobase = (wave & 1)*32;
  int prow = wave >> 1;

  f32x4 acc[2][4];
  #pragma unroll
  for (int mt = 0; mt < 2; ++mt)
    #pragma unroll
    for (int nt = 0; nt < 4; ++nt)
      acc[mt][nt] = (f32x4){0.f,0.f,0.f,0.f};

  const unsigned short* Ap[2];
  #pragma unroll
  for (int mt = 0; mt < 2; ++mt)
    Ap[mt] = Asw + ((size_t)(((wave&1)*2 + mt)*18)*64 + lane)*8;

  int bbase = (prow*TPOS + l15)*LSTR + quad*8;

  #pragma unroll
  for (int tap = 0; tap < 9; ++tap){
    const int sh = (tap/3)*TPOS + (tap%3);
    #pragma unroll
    for (int cc = 0; cc < 2; ++cc){
      int kc = tap*2 + cc;
      bf16x8 a[2], bb[4];
      #pragma unroll
      for (int mt = 0; mt < 2; ++mt)
        a[mt] = *(const bf16x8*)(Ap[mt] + (size_t)kc*512);
      int boff = bbase + sh*LSTR + cc*32;
      #pragma unroll
      for (int nt = 0; nt < 4; ++nt)
        bb[nt] = *(const bf16x8*)&tile[boff + nt*16*LSTR];
      #pragma unroll
      for (int mt = 0; mt < 2; ++mt)
        #pragma unroll
        for (int nt = 0; nt < 4; ++nt)
          acc[mt][nt] = __builtin_amdgcn_mfma_f32_16x16x32_bf16(
              a[mt], bb[nt], acc[mt][nt], 0, 0, 0);
    }
  }

  int gy = r0 + prow;
  #pragma unroll
  for (int mt = 0; mt < 2; ++mt){
    int co4 = cobase + mt*16 + quad*4;
    f32x4 bs = *(const f32x4*)&bias[co4];
    #pragma unroll
    for (int nt = 0; nt < 4; ++nt){
      int gx = c0 + nt*16 + l15;
      size_t gpix = (size_t)gy*W_ + gx;
      float* yo = out + ((size_t)b*64 + co4)*HW_ + gpix;
      f32x4 v = acc[mt][nt] + bs;
      float r0v = v.x + yo[(size_t)0*HW_];
      float r1v = v.y + yo[(size_t)1*HW_];
      float r2v = v.z + yo[(size_t)2*HW_];
      float r3v = v.w + yo[(size_t)3*HW_];
      yo[(size_t)0*HW_] = r0v > 0.f ? r0v : 0.f;
      yo[(size_t)1*HW_] = r1v > 0.f ? r1v : 0.f;
      yo[(size_t)2*HW_] = r2v > 0.f ? r2v : 0.f;
      yo[(size_t)3*HW_] = r3v > 0.f ? r3v : 0.f;
    }
  }
}

// ---------------- gather + 2 MLPs + softmax + weighted sum + scatter (transposed u) ----------------
__global__ __launch_bounds__(256) void attn_kernel(
    const unsigned short* __restrict__ d0t, const unsigned short* __restrict__ r0t,
    const int* __restrict__ pc_idx, const int* __restrict__ nbrs_idx,
    const float* __restrict__ disp,
    const float* __restrict__ dw1, const float* __restrict__ db1,
    const float* __restrict__ dw2, const float* __restrict__ db2,
    const float* __restrict__ rw1, const float* __restrict__ rb1,
    const float* __restrict__ rw2, const float* __restrict__ rb2,
    const float* __restrict__ dbias, const float* __restrict__ rbias,
    unsigned short* __restrict__ u_d, unsigned short* __restrict__ u_r)
{
  __shared__ float feats[9][132];
  __shared__ float ds_s[64], rs_s[64];
  __shared__ float hbuf[2][9][66];
  __shared__ float logitS[2][9];
  __shared__ float attnS[2][9];
  __shared__ int nbrS[9];

  int n = blockIdx.x, b = blockIdx.y;
  int tid = threadIdx.x;
  int s = pc_idx[(size_t)b * Ns_ + n];

  if (tid < 9) nbrS[tid] = nbrs_idx[((size_t)b * Ns_ + n) * K_ + tid];
  __syncthreads();

  for (int e = tid; e < 64 * 10; e += 256){
    int k = e >> 6, c = e & 63;
    if (k < 9){
      int idx = nbrS[k];
      feats[k][c] = b2f(d0t[((size_t)b * HW_ + idx) * 64 + c]);
    } else {
      ds_s[c] = b2f(d0t[((size_t)b * HW_ + s) * 64 + c]);
      rs_s[c] = b2f(r0t[((size_t)b * HW_ + s) * 64 + c]);
    }
  }
  if (tid < 27){
    int m = tid / 9, k = tid % 9;
    feats[k][128 + m] = disp[(((size_t)b * 3 + m) * Ns_ + n) * K_ + k];
  }
  __syncthreads();

  for (int e = tid; e < 64 * 9; e += 256){
    int k = e / 64, c = e % 64;
    float dnn = feats[k][c];
    feats[k][64 + c] = dnn - rs_s[c];
    feats[k][c]      = dnn - ds_s[c];
  }
  __syncthreads();

  for (int job = tid; job < 2 * 9 * 65; job += 256){
    int mlp = job / (9 * 65);
    int r = job % (9 * 65);
    int k = r / 65, j = r % 65;
    const float* w1 = mlp ? rw1 : dw1;
    float h = (mlp ? rb1 : db1)[j];
    for (int d = 0; d < D_; ++d) h += feats[k][d] * w1[(size_t)d * Dh_ + j];
    h = h > 0.f ? h : 0.2f * h;
    hbuf[mlp][k][j] = h;
  }
  __syncthreads();

  for (int job = tid; job < 18; job += 256){
    int mlp = job / 9, k = job % 9;
    const float* w2 = mlp ? rw2 : dw2;
    float l = (mlp ? rb2 : db2)[0];
    for (int j = 0; j < Dh_; ++j) l += hbuf[mlp][k][j] * w2[j];
    logitS[mlp][k] = l;
  }
  __syncthreads();

  if (tid < 2){
    float m = logitS[tid][0];
    for (int k = 1; k < 9; ++k) m = fmaxf(m, logitS[tid][k]);
    float e[9], sum = 0.f;
    for (int k = 0; k < 9; ++k){ e[k] = __expf(logitS[tid][k] - m); sum += e[k]; }
    float inv = 1.f / sum;
    for (int k = 0; k < 9; ++k) attnS[tid][k] = e[k] * inv;
  }
  __syncthreads();

  if (tid < 128){
    int mlp = tid >> 6, c = tid & 63;
    float f = (mlp ? rbias : dbias)[c];
    #pragma unroll
    for (int k = 0; k < 9; ++k){
      float dnn = feats[k][c] + ds_s[c];
      f += attnS[mlp][k] * dnn;
    }
    float base = (c == 0) ? 0.f : (mlp ? rs_s[c] : ds_s[c]);
    unsigned short* u = mlp ? u_r : u_d;
    u[((size_t)b * HW_ + s) * 64 + c] = f2b(base + f);
  }
}

// ---------------- launch ----------------
extern "C" void kernel_launch(void* const* d_in, const int* in_sizes, int n_in,
                              void* d_out, int out_size, void* d_ws, size_t ws_size,
                              hipStream_t stream)
{
  (void)in_sizes; (void)n_in; (void)out_size; (void)ws_size;

  const float* rgb       = (const float*)d_in[0];
  const float* sdepth    = (const float*)d_in[1];
  const int*   pc_idx    = (const int*)d_in[2];
  const int*   nbrs_idx  = (const int*)d_in[3];
  const float* nbrs_disp = (const float*)d_in[4];

  WPtrs wp;
  wp.w[0] = (const float*)d_in[5];   // d_conv0_w
  wp.w[1] = (const float*)d_in[7];   // d_conv1_w
  wp.w[2] = (const float*)d_in[9];   // d_conv2_w
  wp.w[3] = (const float*)d_in[11];  // r_conv0_w
  wp.w[4] = (const float*)d_in[13];  // r_conv1_w
  wp.w[5] = (const float*)d_in[15];  // r_conv2_w
  const float* d_conv0_b = (const float*)d_in[6];
  const float* d_conv1_b = (const float*)d_in[8];
  const float* d_conv2_b = (const float*)d_in[10];
  const float* r_conv0_b = (const float*)d_in[12];
  const float* r_conv1_b = (const float*)d_in[14];
  const float* r_conv2_b = (const float*)d_in[16];
  const float* d_w1 = (const float*)d_in[17];
  const float* d_b1 = (const float*)d_in[18];
  const float* d_w2 = (const float*)d_in[19];
  const float* d_b2 = (const float*)d_in[20];
  const float* r_w1 = (const float*)d_in[21];
  const float* r_b1 = (const float*)d_in[22];
  const float* r_w2 = (const float*)d_in[23];
  const float* r_b2 = (const float*)d_in[24];
  const float* d_bias = (const float*)d_in[25];
  const float* r_bias = (const float*)d_in[26];

  char* ws = (char*)d_ws;
  const size_t TSZ = (size_t)B_ * HW_ * 64 * 2;   // one transposed bf16 tensor
  unsigned short* u_d = (unsigned short*)(ws + 0*TSZ);
  unsigned short* u_r = (unsigned short*)(ws + 1*TSZ);
  unsigned short* d0t = (unsigned short*)(ws + 2*TSZ);
  unsigned short* r0t = (unsigned short*)(ws + 3*TSZ);
  unsigned short* Asw = (unsigned short*)(ws + 4*TSZ);
  const size_t CONV_STRIDE = 4*18*64*8;           // 36864 elems per conv

  prep_w<<<432, 64, 0, stream>>>(wp, Asw);

  float* out = (float*)d_out;
  const size_t OUTSZ = (size_t)B_ * 64 * HW_;

  dim3 cgrid(W_/64, H_/2, B_);
  conv01_mfma<<<cgrid, 256, 0, stream>>>(sdepth, Asw + 0*CONV_STRIDE,
      d_conv0_b, d_conv1_b, d0t, u_d, out);
  conv01_mfma<<<cgrid, 256, 0, stream>>>(rgb,    Asw + 3*CONV_STRIDE,
      r_conv0_b, r_conv1_b, r0t, u_r, out + OUTSZ);

  attn_kernel<<<dim3(Ns_, B_), 256, 0, stream>>>(
      d0t, r0t, pc_idx, nbrs_idx, nbrs_disp,
      d_w1, d_b1, d_w2, d_b2,
      r_w1, r_b1, r_w2, r_b2,
      d_bias, r_bias,
      u_d, u_r);

  conv2_mfma<<<cgrid, 256, 0, stream>>>(u_d, Asw + 2*CONV_STRIDE, d_conv2_b, out);
  conv2_mfma<<<cgrid, 256, 0, stream>>>(u_r, Asw + 5*CONV_STRIDE, r_conv2_b, out + OUTSZ);
}